// Round 3
// baseline (745.367 us; speedup 1.0000x reference)
//
#include <hip/hip_runtime.h>
#include <hip/hip_bf16.h>
#include <math.h>

typedef unsigned short u16;
typedef __attribute__((ext_vector_type(8))) short bf16x8;
typedef __attribute__((ext_vector_type(4))) float f32x4;

#define NTOK 16384
#define LN_EPS 1e-5f

static __device__ __forceinline__ u16 f2bf(float f) {
  unsigned u = __float_as_uint(f);
  u += 0x7fffu + ((u >> 16) & 1u);
  return (u16)(u >> 16);
}
static __device__ __forceinline__ float bf2f(u16 u) {
  return __uint_as_float(((unsigned)u) << 16);
}

// ---------------- weight transpose + bf16 convert: in[K][N] f32 -> out[N][K] bf16
__global__ __launch_bounds__(256) void transpose_bf16(const float* __restrict__ in,
                                                      u16* __restrict__ out,
                                                      int K, int N) {
  __shared__ float tile[32][33];
  int n0 = blockIdx.x * 32, k0 = blockIdx.y * 32;
  int tx = threadIdx.x, ty = threadIdx.y;  // 32 x 8
#pragma unroll
  for (int i = 0; i < 32; i += 8)
    tile[ty + i][tx] = in[(size_t)(k0 + ty + i) * N + n0 + tx];
  __syncthreads();
#pragma unroll
  for (int i = 0; i < 32; i += 8)
    out[(size_t)(n0 + ty + i) * K + k0 + tx] = f2bf(tile[tx][ty + i]);
}

// ---------------- LayerNorm: x[row][1024] f32 -> out bf16
__global__ __launch_bounds__(256) void ln_bf16(const float* __restrict__ x,
                                               const float* __restrict__ g,
                                               const float* __restrict__ be,
                                               u16* __restrict__ out) {
  __shared__ float red[8];
  int row = blockIdx.x;
  int t = threadIdx.x;
  float4 v = ((const float4*)(x + (size_t)row * 1024))[t];
  float s = v.x + v.y + v.z + v.w;
  float ss = v.x * v.x + v.y * v.y + v.z * v.z + v.w * v.w;
#pragma unroll
  for (int i = 1; i < 64; i <<= 1) {
    s += __shfl_xor(s, i);
    ss += __shfl_xor(ss, i);
  }
  int lane = t & 63, wid = t >> 6;
  if (lane == 0) { red[wid] = s; red[4 + wid] = ss; }
  __syncthreads();
  s = red[0] + red[1] + red[2] + red[3];
  ss = red[4] + red[5] + red[6] + red[7];
  float mu = s * (1.0f / 1024.0f);
  float var = ss * (1.0f / 1024.0f) - mu * mu;
  float rs = rsqrtf(var + LN_EPS);
  float4 gv = ((const float4*)g)[t];
  float4 bv = ((const float4*)be)[t];
  ushort4 o;
  o.x = f2bf((v.x - mu) * rs * gv.x + bv.x);
  o.y = f2bf((v.y - mu) * rs * gv.y + bv.y);
  o.z = f2bf((v.z - mu) * rs * gv.z + bv.z);
  o.w = f2bf((v.w - mu) * rs * gv.w + bv.w);
  ((ushort4*)(out + (size_t)row * 1024))[t] = o;
}

// ---------------- per-token head-mixing attention, writes permuted output
__global__ __launch_bounds__(256) void attn_kernel(const u16* __restrict__ qkv,
                                                   u16* __restrict__ operm) {
  int tok = (blockIdx.x << 2) + (threadIdx.x >> 6);
  int lane = threadIdx.x & 63;
  int h = lane >> 2, sub = lane & 3;
  const u16* base = qkv + (size_t)tok * 3072;
  const u16* qp = base + h * 64;
  const u16* kp = base + 1024;
  const u16* vp = base + 2048;

  float sc[4] = {0.f, 0.f, 0.f, 0.f};
#pragma unroll
  for (int d0 = 0; d0 < 64; d0 += 8) {
    bf16x8 q8 = *(const bf16x8*)(qp + d0);
    float qf[8];
#pragma unroll
    for (int j = 0; j < 8; ++j) qf[j] = bf2f((u16)q8[j]);
#pragma unroll
    for (int gi = 0; gi < 4; ++gi) {
      bf16x8 k8 = *(const bf16x8*)(kp + (sub * 4 + gi) * 64 + d0);
#pragma unroll
      for (int j = 0; j < 8; ++j) sc[gi] += qf[j] * bf2f((u16)k8[j]);
    }
  }
  const float scale = 0.125f;
#pragma unroll
  for (int gi = 0; gi < 4; ++gi) sc[gi] *= scale;
  float mx = fmaxf(fmaxf(sc[0], sc[1]), fmaxf(sc[2], sc[3]));
  mx = fmaxf(mx, __shfl_xor(mx, 1));
  mx = fmaxf(mx, __shfl_xor(mx, 2));
  float p[4], sum = 0.f;
#pragma unroll
  for (int gi = 0; gi < 4; ++gi) { p[gi] = expf(sc[gi] - mx); sum += p[gi]; }
  sum += __shfl_xor(sum, 1);
  sum += __shfl_xor(sum, 2);
  float inv = 1.0f / sum;
#pragma unroll
  for (int gi = 0; gi < 4; ++gi) p[gi] *= inv;

  float pall[16];
#pragma unroll
  for (int g = 0; g < 16; ++g)
    pall[g] = __shfl(p[g & 3], (lane & ~3) | (g >> 2));

  float o[16];
#pragma unroll
  for (int j = 0; j < 16; ++j) o[j] = 0.f;
#pragma unroll
  for (int g = 0; g < 16; ++g) {
    bf16x8 v0 = *(const bf16x8*)(vp + g * 64 + sub * 16);
    bf16x8 v1 = *(const bf16x8*)(vp + g * 64 + sub * 16 + 8);
#pragma unroll
    for (int j = 0; j < 8; ++j) {
      o[j] += pall[g] * bf2f((u16)v0[j]);
      o[8 + j] += pall[g] * bf2f((u16)v1[j]);
    }
  }
  int b = tok >> 11, n = tok & 2047;
  size_t off = ((size_t)b << 21) + (size_t)(h * 128 + (n >> 4)) * 1024 +
               (size_t)((n & 15) * 64 + sub * 16);
  bf16x8 w0, w1;
#pragma unroll
  for (int j = 0; j < 8; ++j) {
    w0[j] = (short)f2bf(o[j]);
    w1[j] = (short)f2bf(o[8 + j]);
  }
  *(bf16x8*)(operm + off) = w0;
  *(bf16x8*)(operm + off + 8) = w1;
}

// ---------------- 256x256 counted-vmcnt pipelined GEMM (low-reg-pressure schedule)
// C[M][N] = A[M][K](bf16) * BT[N][K](bf16)^T + bias (+epilogue)
// EPI: 0 = bias -> bf16; 1/3 = bias + res -> f32; 2 = bias + gelu -> bf16
template <int EPI>
__global__ __launch_bounds__(512, 2) void gemm256(const u16* __restrict__ A,
                                                  const u16* __restrict__ BT,
                                                  const float* __restrict__ bias,
                                                  const float* __restrict__ res,
                                                  void* __restrict__ outp,
                                                  int M, int N, int K) {
  __shared__ u16 As[2][256 * 64];
  __shared__ u16 Bs[2][256 * 64];
  const int tid = threadIdx.x;
  const int wid = tid >> 6, lane = tid & 63;
  const int wm = wid >> 2, wn = wid & 3;    // 2 x 4 waves
  const int lrow = lane & 15, lhi = lane >> 4;

  // bijective XCD swizzle (nwg % 8 == 0 for all our grids)
  const int nbx = gridDim.x;
  const int nwg = nbx * gridDim.y;
  const int wg = blockIdx.y * nbx + blockIdx.x;
  const int cpx = nwg >> 3;
  const int swz = (wg & 7) * cpx + (wg >> 3);
  const int bn = swz % nbx, bm = swz / nbx;

  const int NT = K >> 6;

  // staging: region i covers rows i*64..i*64+63 of the 256-row panel;
  // thread covers (row = i*64 + tid>>3, chunk (tid&7)^(row&7))  -> LDS linear slot.
  const int r8 = tid >> 3;
  const int k8s = (tid & 7) ^ (r8 & 7);
  const u16* pA = A + (size_t)(bm * 256 + r8) * K + k8s * 8;
  const u16* pB = BT + (size_t)(bn * 256 + r8) * K + k8s * 8;
  const int ldsbase = wid * 512;

  // issue all 8 global_load_lds for tile t (A 32KB + B 32KB)
  auto stageAll = [&](int t) {
    if (t >= NT) return;
    const size_t koff = (size_t)t * 64;
    u16* la = &As[t & 1][0];
    u16* lb = &Bs[t & 1][0];
#pragma unroll
    for (int i = 0; i < 4; ++i) {
      __builtin_amdgcn_global_load_lds(
          (const __attribute__((address_space(1))) void*)(pA + koff + (size_t)i * 64 * K),
          (__attribute__((address_space(3))) void*)(la + i * 4096 + ldsbase), 16, 0, 0);
    }
#pragma unroll
    for (int i = 0; i < 4; ++i) {
      __builtin_amdgcn_global_load_lds(
          (const __attribute__((address_space(1))) void*)(pB + koff + (size_t)i * 64 * K),
          (__attribute__((address_space(3))) void*)(lb + i * 4096 + ldsbase), 16, 0, 0);
    }
  };

  stageAll(0);  // prologue

  f32x4 acc[8][4] = {};
  const int rbA = wm * 128 + lrow;
  const int rbB = wn * 64 + lrow;
  const int swz8 = (lrow & 7);

  for (int t = 0; t < NT; ++t) {
    stageAll(t + 1);  // into buf (t+1)&1 — read-drained at end of tile t-1
    if (t + 1 < NT) {
      asm volatile("s_waitcnt vmcnt(8)" ::: "memory");  // exactly t+1's 8 loads newer
    } else {
      asm volatile("s_waitcnt vmcnt(0)" ::: "memory");
    }
    __builtin_amdgcn_s_barrier();          // tile t staged & visible block-wide
    __builtin_amdgcn_sched_barrier(0);

    const u16* Ab = &As[t & 1][0];
    const u16* Bb = &Bs[t & 1][0];
#pragma unroll
    for (int s = 0; s < 2; ++s) {
      const int sl = ((s * 4 + lhi) ^ swz8) << 3;
      bf16x8 bfv[4];
#pragma unroll
      for (int n = 0; n < 4; ++n)
        bfv[n] = *(const bf16x8*)(Bb + (rbB + n * 16) * 64 + sl);
#pragma unroll
      for (int q = 0; q < 4; ++q) {
        bf16x8 a0 = *(const bf16x8*)(Ab + (rbA + (2 * q) * 16) * 64 + sl);
        bf16x8 a1 = *(const bf16x8*)(Ab + (rbA + (2 * q + 1) * 16) * 64 + sl);
        __builtin_amdgcn_s_setprio(1);
#pragma unroll
        for (int n = 0; n < 4; ++n) {
          acc[2 * q][n] = __builtin_amdgcn_mfma_f32_16x16x32_bf16(a0, bfv[n], acc[2 * q][n], 0, 0, 0);
          acc[2 * q + 1][n] = __builtin_amdgcn_mfma_f32_16x16x32_bf16(a1, bfv[n], acc[2 * q + 1][n], 0, 0, 0);
        }
        __builtin_amdgcn_s_setprio(0);
      }
    }

    asm volatile("s_waitcnt lgkmcnt(0)" ::: "memory");
    __builtin_amdgcn_sched_barrier(0);
    __builtin_amdgcn_s_barrier();          // buf (t&1) read-drained block-wide
    __builtin_amdgcn_sched_barrier(0);
  }

  // epilogue
  const size_t crow0 = (size_t)bm * 256 + (size_t)wm * 128;
  const int ccol0 = bn * 256 + wn * 64;
#pragma unroll
  for (int n = 0; n < 4; ++n) {
    const int col = ccol0 + n * 16 + lrow;
    const float bb = bias[col];
#pragma unroll
    for (int m = 0; m < 8; ++m) {
#pragma unroll
      for (int r = 0; r < 4; ++r) {
        const size_t row = crow0 + m * 16 + lhi * 4 + r;
        const size_t idx = row * (size_t)N + col;
        float val = acc[m][n][r] + bb;
        if (EPI == 1 || EPI == 3) val += res[idx];
        if (EPI == 2) val = 0.5f * val * (1.0f + erff(val * 0.70710678118654752f));
        if (EPI == 0 || EPI == 2)
          ((u16*)outp)[idx] = f2bf(val);
        else
          ((float*)outp)[idx] = val;
      }
    }
  }
}

extern "C" void kernel_launch(void* const* d_in, const int* in_sizes, int n_in,
                              void* d_out, int out_size, void* d_ws, size_t ws_size,
                              hipStream_t stream) {
  const float* x = (const float*)d_in[0];
  const float* w_qkv = (const float*)d_in[1];
  const float* b_qkv = (const float*)d_in[2];
  const float* w_proj = (const float*)d_in[3];
  const float* b_proj = (const float*)d_in[4];
  const float* w_fc1 = (const float*)d_in[5];
  const float* b_fc1 = (const float*)d_in[6];
  const float* w_fc2 = (const float*)d_in[7];
  const float* b_fc2 = (const float*)d_in[8];
  const float* g1 = (const float*)d_in[9];
  const float* be1 = (const float*)d_in[10];
  const float* g2 = (const float*)d_in[11];
  const float* be2 = (const float*)d_in[12];
  float* out = (float*)d_out;

  char* ws = (char*)d_ws;
  u16* wqkvT = (u16*)ws; ws += (size_t)3072 * 1024 * 2;
  u16* wprojT = (u16*)ws; ws += (size_t)1024 * 1024 * 2;
  u16* wfc1T = (u16*)ws; ws += (size_t)4096 * 1024 * 2;
  u16* wfc2T = (u16*)ws; ws += (size_t)1024 * 4096 * 2;
  u16* hbuf = (u16*)ws; ws += (size_t)NTOK * 1024 * 2;   // h / operm / h2 (reused)
  u16* big = (u16*)ws;                                    // qkv then fc1 activations

  transpose_bf16<<<dim3(3072 / 32, 1024 / 32), dim3(32, 8), 0, stream>>>(w_qkv, wqkvT, 1024, 3072);
  transpose_bf16<<<dim3(1024 / 32, 1024 / 32), dim3(32, 8), 0, stream>>>(w_proj, wprojT, 1024, 1024);
  transpose_bf16<<<dim3(4096 / 32, 1024 / 32), dim3(32, 8), 0, stream>>>(w_fc1, wfc1T, 1024, 4096);
  transpose_bf16<<<dim3(1024 / 32, 4096 / 32), dim3(32, 8), 0, stream>>>(w_fc2, wfc2T, 4096, 1024);

  ln_bf16<<<NTOK, 256, 0, stream>>>(x, g1, be1, hbuf);

  gemm256<0><<<dim3(3072 / 256, NTOK / 256), 512, 0, stream>>>(hbuf, wqkvT, b_qkv, nullptr, big, NTOK, 3072, 1024);

  attn_kernel<<<NTOK / 4, 256, 0, stream>>>(big, hbuf);

  gemm256<1><<<dim3(1024 / 256, NTOK / 256), 512, 0, stream>>>(hbuf, wprojT, b_proj, x, out, NTOK, 1024, 1024);

  ln_bf16<<<NTOK, 256, 0, stream>>>(out, g2, be2, hbuf);

  gemm256<2><<<dim3(4096 / 256, NTOK / 256), 512, 0, stream>>>(hbuf, wfc1T, b_fc1, nullptr, big, NTOK, 4096, 1024);

  gemm256<3><<<dim3(1024 / 256, NTOK / 256), 512, 0, stream>>>(big, wfc2T, b_fc2, out, out, NTOK, 1024, 4096);
}

// Round 4
// 625.570 us; speedup vs baseline: 1.1915x; 1.1915x over previous
//
#include <hip/hip_runtime.h>
#include <hip/hip_bf16.h>
#include <math.h>

typedef unsigned short u16;
typedef __attribute__((ext_vector_type(8))) short bf16x8;
typedef __attribute__((ext_vector_type(4))) float f32x4;

#define NTOK 16384
#define LN_EPS 1e-5f

static __device__ __forceinline__ u16 f2bf(float f) {
  unsigned u = __float_as_uint(f);
  u += 0x7fffu + ((u >> 16) & 1u);
  return (u16)(u >> 16);
}
static __device__ __forceinline__ float bf2f(u16 u) {
  return __uint_as_float(((unsigned)u) << 16);
}

// ---------------- weight transpose + bf16 convert: in[K][N] f32 -> out[N][K] bf16
__global__ __launch_bounds__(256) void transpose_bf16(const float* __restrict__ in,
                                                      u16* __restrict__ out,
                                                      int K, int N) {
  __shared__ float tile[32][33];
  int n0 = blockIdx.x * 32, k0 = blockIdx.y * 32;
  int tx = threadIdx.x, ty = threadIdx.y;  // 32 x 8
#pragma unroll
  for (int i = 0; i < 32; i += 8)
    tile[ty + i][tx] = in[(size_t)(k0 + ty + i) * N + n0 + tx];
  __syncthreads();
#pragma unroll
  for (int i = 0; i < 32; i += 8)
    out[(size_t)(n0 + ty + i) * K + k0 + tx] = f2bf(tile[tx][ty + i]);
}

// ---------------- LayerNorm: x[row][1024] f32 -> out bf16
__global__ __launch_bounds__(256) void ln_bf16(const float* __restrict__ x,
                                               const float* __restrict__ g,
                                               const float* __restrict__ be,
                                               u16* __restrict__ out) {
  __shared__ float red[8];
  int row = blockIdx.x;
  int t = threadIdx.x;
  float4 v = ((const float4*)(x + (size_t)row * 1024))[t];
  float s = v.x + v.y + v.z + v.w;
  float ss = v.x * v.x + v.y * v.y + v.z * v.z + v.w * v.w;
#pragma unroll
  for (int i = 1; i < 64; i <<= 1) {
    s += __shfl_xor(s, i);
    ss += __shfl_xor(ss, i);
  }
  int lane = t & 63, wid = t >> 6;
  if (lane == 0) { red[wid] = s; red[4 + wid] = ss; }
  __syncthreads();
  s = red[0] + red[1] + red[2] + red[3];
  ss = red[4] + red[5] + red[6] + red[7];
  float mu = s * (1.0f / 1024.0f);
  float var = ss * (1.0f / 1024.0f) - mu * mu;
  float rs = rsqrtf(var + LN_EPS);
  float4 gv = ((const float4*)g)[t];
  float4 bv = ((const float4*)be)[t];
  ushort4 o;
  o.x = f2bf((v.x - mu) * rs * gv.x + bv.x);
  o.y = f2bf((v.y - mu) * rs * gv.y + bv.y);
  o.z = f2bf((v.z - mu) * rs * gv.z + bv.z);
  o.w = f2bf((v.w - mu) * rs * gv.w + bv.w);
  ((ushort4*)(out + (size_t)row * 1024))[t] = o;
}

// ---------------- per-token head-mixing attention, writes permuted output
__global__ __launch_bounds__(256) void attn_kernel(const u16* __restrict__ qkv,
                                                   u16* __restrict__ operm) {
  int tok = (blockIdx.x << 2) + (threadIdx.x >> 6);
  int lane = threadIdx.x & 63;
  int h = lane >> 2, sub = lane & 3;
  const u16* base = qkv + (size_t)tok * 3072;
  const u16* qp = base + h * 64;
  const u16* kp = base + 1024;
  const u16* vp = base + 2048;

  float sc[4] = {0.f, 0.f, 0.f, 0.f};
#pragma unroll
  for (int d0 = 0; d0 < 64; d0 += 8) {
    bf16x8 q8 = *(const bf16x8*)(qp + d0);
    float qf[8];
#pragma unroll
    for (int j = 0; j < 8; ++j) qf[j] = bf2f((u16)q8[j]);
#pragma unroll
    for (int gi = 0; gi < 4; ++gi) {
      bf16x8 k8 = *(const bf16x8*)(kp + (sub * 4 + gi) * 64 + d0);
#pragma unroll
      for (int j = 0; j < 8; ++j) sc[gi] += qf[j] * bf2f((u16)k8[j]);
    }
  }
  const float scale = 0.125f;
#pragma unroll
  for (int gi = 0; gi < 4; ++gi) sc[gi] *= scale;
  float mx = fmaxf(fmaxf(sc[0], sc[1]), fmaxf(sc[2], sc[3]));
  mx = fmaxf(mx, __shfl_xor(mx, 1));
  mx = fmaxf(mx, __shfl_xor(mx, 2));
  float p[4], sum = 0.f;
#pragma unroll
  for (int gi = 0; gi < 4; ++gi) { p[gi] = expf(sc[gi] - mx); sum += p[gi]; }
  sum += __shfl_xor(sum, 1);
  sum += __shfl_xor(sum, 2);
  float inv = 1.0f / sum;
#pragma unroll
  for (int gi = 0; gi < 4; ++gi) p[gi] *= inv;

  float pall[16];
#pragma unroll
  for (int g = 0; g < 16; ++g)
    pall[g] = __shfl(p[g & 3], (lane & ~3) | (g >> 2));

  float o[16];
#pragma unroll
  for (int j = 0; j < 16; ++j) o[j] = 0.f;
#pragma unroll
  for (int g = 0; g < 16; ++g) {
    bf16x8 v0 = *(const bf16x8*)(vp + g * 64 + sub * 16);
    bf16x8 v1 = *(const bf16x8*)(vp + g * 64 + sub * 16 + 8);
#pragma unroll
    for (int j = 0; j < 8; ++j) {
      o[j] += pall[g] * bf2f((u16)v0[j]);
      o[8 + j] += pall[g] * bf2f((u16)v1[j]);
    }
  }
  int b = tok >> 11, n = tok & 2047;
  size_t off = ((size_t)b << 21) + (size_t)(h * 128 + (n >> 4)) * 1024 +
               (size_t)((n & 15) * 64 + sub * 16);
  bf16x8 w0, w1;
#pragma unroll
  for (int j = 0; j < 8; ++j) {
    w0[j] = (short)f2bf(o[j]);
    w1[j] = (short)f2bf(o[8 + j]);
  }
  *(bf16x8*)(operm + off) = w0;
  *(bf16x8*)(operm + off + 8) = w1;
}

// ---------------- 256x256 8-phase-style GEMM with LDS-staged coalesced epilogue
// C[M][N] = A[M][K](bf16) * BT[N][K](bf16)^T + bias (+epilogue)
// EPI: 0 = bias -> bf16; 1/3 = bias + res -> f32; 2 = bias + gelu -> bf16
template <int EPI>
__global__ __launch_bounds__(512, 2) void gemm256(const u16* __restrict__ A,
                                                  const u16* __restrict__ BT,
                                                  const float* __restrict__ bias,
                                                  const float* __restrict__ res,
                                                  void* __restrict__ outp,
                                                  int M, int N, int K) {
  __shared__ __align__(16) u16 SLDS[65536];  // 128 KiB: A dbuf 64K | B dbuf 64K; reused for C stage
  u16* As = SLDS;           // [2][16384]
  u16* Bs = SLDS + 32768;   // [2][16384]
  const int tid = threadIdx.x;
  const int wid = tid >> 6, lane = tid & 63;
  const int wm = wid >> 2, wn = wid & 3;    // 2 x 4 waves
  const int lrow = lane & 15, lhi = lane >> 4;

  // bijective XCD swizzle (nwg % 8 == 0 for all our grids)
  const int nbx = gridDim.x;
  const int nwg = nbx * gridDim.y;
  const int wg = blockIdx.y * nbx + blockIdx.x;
  const int cpx = nwg >> 3;
  const int swz = (wg & 7) * cpx + (wg >> 3);
  const int bn = swz % nbx, bm = swz / nbx;

  const int NT = K >> 6;

  // staging geometry (proven conflict-free in rounds 1-3):
  // chunk i covers rows i*64..i*64+63; thread -> (row = i*64 + tid>>3, k8 = (tid&7)^(row&7))
  const int r8 = tid >> 3;
  const int k8s = (tid & 7) ^ (r8 & 7);
  const u16* pA = A + (size_t)(bm * 256 + r8) * K + k8s * 8;
  const u16* pB = BT + (size_t)(bn * 256 + r8) * K + k8s * 8;
  const int ldsbase = wid * 512;

  auto stageM = [&](const u16* p, u16* lb, int t) {
    if (t >= NT) return;
    const size_t koff = (size_t)t * 64;
    u16* l = lb + (t & 1) * 16384;
#pragma unroll
    for (int i = 0; i < 4; ++i) {
      __builtin_amdgcn_global_load_lds(
          (const __attribute__((address_space(1))) void*)(p + koff + (size_t)i * 64 * K),
          (__attribute__((address_space(3))) void*)(l + i * 4096 + ldsbase), 16, 0, 0);
    }
  };

  stageM(pA, As, 0);
  stageM(pB, Bs, 0);

  f32x4 acc[8][4] = {};
  const int rbA = wm * 128 + lrow;
  const int rbB = wn * 64 + lrow;
  const int swz8 = lrow & 7;
  const int sl0 = ((0 + lhi) ^ swz8) << 3;
  const int sl1 = ((4 + lhi) ^ swz8) << 3;

  for (int t = 0; t < NT; ++t) {
    asm volatile("s_waitcnt vmcnt(0)" ::: "memory");  // tile t's 8 loads: issued >=2 phases ago (warm)
    __builtin_amdgcn_s_barrier();                      // tile t visible block-wide

    const u16* Ab = As + (t & 1) * 16384;
    const u16* Bb = Bs + (t & 1) * 16384;
    bf16x8 bfv[4][2];
#pragma unroll
    for (int q = 0; q < 4; ++q) {
      // --- phase q: ds_reads for quadrant q (+ all B at q==0), stage half of t+1 (q<2)
      if (q == 0) {
#pragma unroll
        for (int n = 0; n < 4; ++n) {
          bfv[n][0] = *(const bf16x8*)(Bb + (rbB + n * 16) * 64 + sl0);
          bfv[n][1] = *(const bf16x8*)(Bb + (rbB + n * 16) * 64 + sl1);
        }
      }
      bf16x8 af[2][2];
#pragma unroll
      for (int j = 0; j < 2; ++j) {
        const int row = rbA + (2 * q + j) * 16;
        af[j][0] = *(const bf16x8*)(Ab + row * 64 + sl0);
        af[j][1] = *(const bf16x8*)(Ab + row * 64 + sl1);
      }
      if (q == 0) stageM(pA, As, t + 1);
      if (q == 1) stageM(pB, Bs, t + 1);
      __builtin_amdgcn_s_barrier();
      asm volatile("s_waitcnt lgkmcnt(0)" ::: "memory");
      __builtin_amdgcn_sched_barrier(0);
      __builtin_amdgcn_s_setprio(1);
#pragma unroll
      for (int j = 0; j < 2; ++j)
#pragma unroll
        for (int n = 0; n < 4; ++n) {
          acc[2 * q + j][n] = __builtin_amdgcn_mfma_f32_16x16x32_bf16(af[j][0], bfv[n][0], acc[2 * q + j][n], 0, 0, 0);
          acc[2 * q + j][n] = __builtin_amdgcn_mfma_f32_16x16x32_bf16(af[j][1], bfv[n][1], acc[2 * q + j][n], 0, 0, 0);
        }
      __builtin_amdgcn_s_setprio(0);
      __builtin_amdgcn_s_barrier();
    }
  }

  // ---------------- epilogue: stage C in LDS, stream out coalesced
  __syncthreads();
  const int crow0 = bm * 256;
  const int ccol0 = bn * 256;

  if (EPI == 0 || EPI == 2) {
    u16* Cl = SLDS;  // [256][256] u16, col bits 4-5 XOR'd by lhi (row bits 2-3)
#pragma unroll
    for (int n = 0; n < 4; ++n) {
      const int col = wn * 64 + n * 16 + lrow;
      const float bb = bias[ccol0 + col];
#pragma unroll
      for (int m = 0; m < 8; ++m) {
#pragma unroll
        for (int r = 0; r < 4; ++r) {
          const int row = wm * 128 + m * 16 + lhi * 4 + r;
          float val = acc[m][n][r] + bb;
          if (EPI == 2) val = 0.5f * val * (1.0f + erff(val * 0.70710678118654752f));
          Cl[row * 256 + (col ^ ((row & 12) << 2))] = f2bf(val);
        }
      }
    }
    __syncthreads();
    const int rl = tid >> 5, ch = tid & 31;
#pragma unroll
    for (int it = 0; it < 16; ++it) {
      const int row = it * 16 + rl;
      const int pch = ch ^ (((row >> 2) & 3) << 1);
      bf16x8 v = *(const bf16x8*)(Cl + row * 256 + pch * 8);
      *(bf16x8*)((u16*)outp + (size_t)(crow0 + row) * N + ccol0 + ch * 8) = v;
    }
  } else {
    float* Cf = (float*)SLDS;  // [128][256] f32, col bit 4 XOR'd by row bit 2
#pragma unroll
    for (int h = 0; h < 2; ++h) {
      if (h) __syncthreads();
      if (wm == h) {
#pragma unroll
        for (int n = 0; n < 4; ++n) {
          const int col = wn * 64 + n * 16 + lrow;
          const float bb = bias[ccol0 + col];
#pragma unroll
          for (int m = 0; m < 8; ++m)
#pragma unroll
            for (int r = 0; r < 4; ++r) {
              const int row = m * 16 + lhi * 4 + r;  // 0..127
              Cf[row * 256 + (col ^ ((row & 4) << 2))] = acc[m][n][r] + bb;
            }
        }
      }
      __syncthreads();
      const int rl = tid >> 6, ch = tid & 63;
#pragma unroll
      for (int it = 0; it < 16; ++it) {
        const int row = it * 8 + rl;
        const int pch = ch ^ (((row >> 2) & 1) << 2);
        f32x4 v = *(const f32x4*)(Cf + row * 256 + pch * 4);
        const size_t gidx = (size_t)(crow0 + h * 128 + row) * N + ccol0 + ch * 4;
        const f32x4 rv = *(const f32x4*)(res + gidx);
        v = v + rv;
        *(f32x4*)((float*)outp + gidx) = v;
      }
    }
  }
}

extern "C" void kernel_launch(void* const* d_in, const int* in_sizes, int n_in,
                              void* d_out, int out_size, void* d_ws, size_t ws_size,
                              hipStream_t stream) {
  const float* x = (const float*)d_in[0];
  const float* w_qkv = (const float*)d_in[1];
  const float* b_qkv = (const float*)d_in[2];
  const float* w_proj = (const float*)d_in[3];
  const float* b_proj = (const float*)d_in[4];
  const float* w_fc1 = (const float*)d_in[5];
  const float* b_fc1 = (const float*)d_in[6];
  const float* w_fc2 = (const float*)d_in[7];
  const float* b_fc2 = (const float*)d_in[8];
  const float* g1 = (const float*)d_in[9];
  const float* be1 = (const float*)d_in[10];
  const float* g2 = (const float*)d_in[11];
  const float* be2 = (const float*)d_in[12];
  float* out = (float*)d_out;

  char* ws = (char*)d_ws;
  u16* wqkvT = (u16*)ws; ws += (size_t)3072 * 1024 * 2;
  u16* wprojT = (u16*)ws; ws += (size_t)1024 * 1024 * 2;
  u16* wfc1T = (u16*)ws; ws += (size_t)4096 * 1024 * 2;
  u16* wfc2T = (u16*)ws; ws += (size_t)1024 * 4096 * 2;
  u16* hbuf = (u16*)ws; ws += (size_t)NTOK * 1024 * 2;   // h / operm / h2 (reused)
  u16* big = (u16*)ws;                                    // qkv then fc1 activations

  transpose_bf16<<<dim3(3072 / 32, 1024 / 32), dim3(32, 8), 0, stream>>>(w_qkv, wqkvT, 1024, 3072);
  transpose_bf16<<<dim3(1024 / 32, 1024 / 32), dim3(32, 8), 0, stream>>>(w_proj, wprojT, 1024, 1024);
  transpose_bf16<<<dim3(4096 / 32, 1024 / 32), dim3(32, 8), 0, stream>>>(w_fc1, wfc1T, 1024, 4096);
  transpose_bf16<<<dim3(1024 / 32, 4096 / 32), dim3(32, 8), 0, stream>>>(w_fc2, wfc2T, 4096, 1024);

  ln_bf16<<<NTOK, 256, 0, stream>>>(x, g1, be1, hbuf);

  gemm256<0><<<dim3(3072 / 256, NTOK / 256), 512, 0, stream>>>(hbuf, wqkvT, b_qkv, nullptr, big, NTOK, 3072, 1024);

  attn_kernel<<<NTOK / 4, 256, 0, stream>>>(big, hbuf);

  gemm256<1><<<dim3(1024 / 256, NTOK / 256), 512, 0, stream>>>(hbuf, wprojT, b_proj, x, out, NTOK, 1024, 1024);

  ln_bf16<<<NTOK, 256, 0, stream>>>(out, g2, be2, hbuf);

  gemm256<2><<<dim3(4096 / 256, NTOK / 256), 512, 0, stream>>>(hbuf, wfc1T, b_fc1, nullptr, big, NTOK, 4096, 1024);

  gemm256<3><<<dim3(1024 / 256, NTOK / 256), 512, 0, stream>>>(big, wfc2T, b_fc2, out, out, NTOK, 1024, 4096);
}